// Round 1
// baseline (301.738 us; speedup 1.0000x reference)
//
#include <hip/hip_runtime.h>
#include <math.h>

// Problem constants
#define NB 8
#define CH 64
#define IN_SZ 128
#define PLANE (IN_SZ*IN_SZ)          // 16384
#define TAPS 12

// ws layout (floats):
//   y0   : NB*CH*PLANE            = 8388608 floats @ byte 0
//   wt   : 64*9*64 = 36864 floats @ byte 33554432   (layout [ci][tap][co])
//   f1d  : 24 floats              @ byte 33701888   (up1d[12], dn1d[12])
#define Y0_BYTES   (NB*CH*PLANE*4)
#define WT_BYTES   (64*9*64*4)

// ---------------------------------------------------------------------------
// prep: transpose conv weights OIHW -> [ci][ky*3+kx][co], extract separable
// 1-D filters from the 12x12 outer-product filters.
// f1d[k] = f2[k][5] / sqrt(f2[5][5])  (global sign ambiguity cancels: filter
// is applied once per dim in the separable conv, g⊗g == f⊗f).
// ---------------------------------------------------------------------------
__global__ __launch_bounds__(256) void prep_kernel(
    const float* __restrict__ w,     // [64][64][3][3]
    const float* __restrict__ up2,   // [12][12]
    const float* __restrict__ dn2,   // [12][12]
    float* __restrict__ wt,          // [64][9][64]
    float* __restrict__ f1d) {       // [24]
  int t = blockIdx.x * 256 + threadIdx.x;
  if (t < 64*9*64) {
    int co = t & 63;
    int rest = t >> 6;          // ci*9 + ky*3 + kx
    int kx = rest % 3;
    int ky = (rest / 3) % 3;
    int ci = rest / 9;
    wt[t] = w[((co*64 + ci)*3 + ky)*3 + kx];
  }
  if (blockIdx.x == 0) {
    if (threadIdx.x < 12) {
      f1d[threadIdx.x] = up2[threadIdx.x*12 + 5] / sqrtf(up2[5*12 + 5]);
    } else if (threadIdx.x < 24) {
      int k = threadIdx.x - 12;
      f1d[threadIdx.x] = dn2[k*12 + 5] / sqrtf(dn2[5*12 + 5]);
    }
  }
}

// ---------------------------------------------------------------------------
// conv3x3: direct conv, 64->64 channels, "same" padding, + conv_b + bias.
// Grid: 8 batches * 64 tiles(16x16 px) * 2 co-halves = 1024 blocks, 256 thr.
// Each thread: one pixel, 32 output-channel accumulators.
// Weights are wave-uniform (same address all lanes) -> scalar loads.
// x reads are per-lane, 3x3 neighborhood, L1-cached.
// ---------------------------------------------------------------------------
__global__ __launch_bounds__(256) void conv3x3_kernel(
    const float* __restrict__ x,     // [8][64][128][128]
    const float* __restrict__ wt,    // [64][9][64]
    const float* __restrict__ cb,    // [64]
    const float* __restrict__ bias,  // [64]
    float* __restrict__ y0) {        // [8][64][128][128]
  int blk  = blockIdx.x;
  int half = blk & 1;
  int tile = (blk >> 1) & 63;
  int b    = blk >> 7;
  int ty = tile >> 3, tx = tile & 7;
  int ly = threadIdx.x >> 4, lx = threadIdx.x & 15;
  int py = ty*16 + ly, px = tx*16 + lx;

  const float* xb = x + b*(CH*PLANE) + py*IN_SZ + px;

  float acc[32];
#pragma unroll
  for (int i = 0; i < 32; ++i) acc[i] = 0.f;

  const float* wbase = wt + half*32;

  for (int ci = 0; ci < 64; ++ci) {
    const float* xc = xb + ci*PLANE;
    float xv[9];
#pragma unroll
    for (int dy = 0; dy < 3; ++dy) {
      int yy = py + dy - 1;
#pragma unroll
      for (int dx = 0; dx < 3; ++dx) {
        int xx = px + dx - 1;
        bool ok = ((unsigned)yy < 128u) & ((unsigned)xx < 128u);
        xv[dy*3 + dx] = ok ? xc[(dy-1)*IN_SZ + (dx-1)] : 0.f;
      }
    }
    const float* wci = wbase + ci*(9*64);
#pragma unroll
    for (int tap = 0; tap < 9; ++tap) {
      float xt = xv[tap];
      const float* wp = wci + tap*64;
#pragma unroll
      for (int c = 0; c < 32; ++c) acc[c] += xt * wp[c];
    }
  }

  int co0 = half*32;
  float* yp = y0 + (b*CH + co0)*PLANE + py*IN_SZ + px;
#pragma unroll
  for (int c = 0; c < 32; ++c) {
    yp[c*PLANE] = acc[c] + cb[co0 + c] + bias[co0 + c];
  }
}

// ---------------------------------------------------------------------------
// upfirdn: fused  repeat(2x) -> conv(up 12x12) -> lrelu*gain -> conv(dn 12x12)
//          -> ::2 downsample, separable filters, per 32x32-output tile.
// Grid: 512 planes * 16 tiles = 8192 blocks, 256 threads.
//
// 256-grid index math: r[t] = y0[t>>1]; upc[q] = sum_k r[q-5+k]*up1[k];
// z = lrelu(upc)*gain (zeroed outside [0,256) -- dn-conv zero padding);
// out[i] = sum_k z[2i-5+k]*dn1[k].
// Tile needs: y0 rows/cols [i0-5, i0+37] (43), z rows/cols [2*i0-5, +68] (74).
// All floor-divides arranged as (even + nonneg)>>1 so plain shifts are exact.
// ---------------------------------------------------------------------------
__global__ __launch_bounds__(256) void upfirdn_kernel(
    const float* __restrict__ y0,    // [512][128][128]
    const float* __restrict__ f1d,   // [24]
    float* __restrict__ out) {       // [512][128][128]
  __shared__ float ylds[43*44];      // y0 tile, pitch 44 (col 43 = pad)
  __shared__ float Hlds[44*76];      // H pass, 43 rows used (+1 pad), pitch 76
  __shared__ float zlds[74*76];      // z tile, pitch 76
  __shared__ float dhlds[74*32];     // dn horizontal pass

  int tid   = threadIdx.x;
  int blk   = blockIdx.x;
  int tile  = blk & 15;
  int plane = blk >> 4;
  int ty = tile >> 2, tx = tile & 3;
  int i0 = ty*32, j0 = tx*32;
  const float* yp = y0 + plane*PLANE;

  float up1[12], dn1[12];
#pragma unroll
  for (int k = 0; k < 12; ++k) { up1[k] = f1d[k]; dn1[k] = f1d[12+k]; }

  // phase 1: load y0 tile (zero-pad outside [0,128)^2; this padding exactly
  // reproduces BOTH the repeat-grid zero pad and y0-range pad since
  // t in [0,256) <=> (t>>1) in [0,128) with arithmetic floor shift).
  for (int p = tid; p < 43*43; p += 256) {
    int r = p / 43, c = p - r*43;
    int gy = i0 - 5 + r, gx = j0 - 5 + c;
    float v = 0.f;
    if (((unsigned)gy < 128u) && ((unsigned)gx < 128u)) v = yp[gy*IN_SZ + gx];
    ylds[r*44 + c] = v;
  }
  __syncthreads();

  // phase 2: horizontal up-pass. H[m][qxi] = sum_k up1[k]*y0[m][(qx-5+k)>>1].
  // Grouped 4 outputs along qxi: base col = 2G (derivation: Qx0-5 = 2*j0-10
  // even, so tile col = 2G + ((s+k)>>1), compile-time indices).
  for (int p = tid; p < 43*19; p += 256) {
    int m = p / 19, G = p - m*19;
    const float* yr = &ylds[m*44 + 2*G];
    float4 ya = *(const float4*)(yr);
    float4 yb = *(const float4*)(yr + 4);
    float yreg[8] = {ya.x, ya.y, ya.z, ya.w, yb.x, yb.y, yb.z, yb.w};
    float hv[4];
#pragma unroll
    for (int s = 0; s < 4; ++s) {
      float a = 0.f;
#pragma unroll
      for (int k = 0; k < 12; ++k) a += up1[k] * yreg[(s+k) >> 1];
      hv[s] = a;
    }
    int qxi0 = 4*G;
    float* hp = &Hlds[m*76 + qxi0];
    if (qxi0 < 72) {
      *(float4*)hp = make_float4(hv[0], hv[1], hv[2], hv[3]);
    } else {                       // G == 18: only qxi 72,73 exist
      hp[0] = hv[0]; hp[1] = hv[1];
    }
  }
  __syncthreads();

  // phase 3: vertical up-pass + leaky-relu + gain + boundary zeroing -> z.
  // Grouped 4 outputs along qyi: H row = 2g + ((s+k)>>1).
  int Qy0 = 2*i0 - 5, Qx0 = 2*j0 - 5;
  for (int p = tid; p < 19*74; p += 256) {
    int g = p / 74, qxi = p - g*74;
    float hreg[8];
#pragma unroll
    for (int r = 0; r < 8; ++r) hreg[r] = Hlds[(2*g + r)*76 + qxi];
    int qx = Qx0 + qxi;
    bool xok = ((unsigned)qx < 256u);
#pragma unroll
    for (int s = 0; s < 4; ++s) {
      int qyi = 4*g + s;
      if (qyi < 74) {
        float a = 0.f;
#pragma unroll
        for (int k = 0; k < 12; ++k) a += up1[k] * hreg[(s+k) >> 1];
        a = (a >= 0.f ? a : 0.2f*a) * 1.4142135623730951f;
        int qy = Qy0 + qyi;
        bool ok = xok && ((unsigned)qy < 256u);
        zlds[qyi*76 + qxi] = ok ? a : 0.f;
      }
    }
  }
  __syncthreads();

  // phase 4: horizontal dn-pass at even output columns only.
  // dh[qyi][j] = sum_k dn1[k] * z[qyi][2j + k]  (tile col = 2j+k).
  // Grouped 4 outputs along j: reads 18 consecutive z floats.
  for (int p = tid; p < 74*8; p += 256) {
    int qyi = p >> 3, gj = p & 7;
    const float* zr = &zlds[qyi*76 + 8*gj];
    float4 z0 = *(const float4*)(zr);
    float4 z1 = *(const float4*)(zr + 4);
    float4 z2 = *(const float4*)(zr + 8);
    float4 z3 = *(const float4*)(zr + 12);
    float2 z4 = *(const float2*)(zr + 16);
    float zreg[18] = {z0.x,z0.y,z0.z,z0.w, z1.x,z1.y,z1.z,z1.w,
                      z2.x,z2.y,z2.z,z2.w, z3.x,z3.y,z3.z,z3.w, z4.x,z4.y};
#pragma unroll
    for (int s = 0; s < 4; ++s) {
      float a = 0.f;
#pragma unroll
      for (int k = 0; k < 12; ++k) a += dn1[k] * zreg[2*s + k];
      dhlds[qyi*32 + 4*gj + s] = a;
    }
  }
  __syncthreads();

  // phase 5: vertical dn-pass at even output rows, write result.
  // out[i][j] = sum_k dn1[k] * dh[2i + k][j]. Grouped 4 outputs along i.
  {
    int p = tid;                    // exactly 256 groups
    int gi = p >> 5, j = p & 31;
    float dreg[18];
#pragma unroll
    for (int r = 0; r < 18; ++r) dreg[r] = dhlds[(8*gi + r)*32 + j];
    float* op = out + plane*PLANE + (i0 + 4*gi)*IN_SZ + (j0 + j);
#pragma unroll
    for (int s = 0; s < 4; ++s) {
      float a = 0.f;
#pragma unroll
      for (int k = 0; k < 12; ++k) a += dn1[k] * dreg[2*s + k];
      op[s*IN_SZ] = a;
    }
  }
}

// ---------------------------------------------------------------------------
extern "C" void kernel_launch(void* const* d_in, const int* in_sizes, int n_in,
                              void* d_out, int out_size, void* d_ws, size_t ws_size,
                              hipStream_t stream) {
  const float* x      = (const float*)d_in[0];
  const float* conv_w = (const float*)d_in[1];
  const float* conv_b = (const float*)d_in[2];
  const float* bias   = (const float*)d_in[3];
  const float* up2    = (const float*)d_in[4];
  const float* dn2    = (const float*)d_in[5];
  float* outp = (float*)d_out;

  char* ws = (char*)d_ws;
  float* y0  = (float*)(ws);
  float* wt  = (float*)(ws + Y0_BYTES);
  float* f1d = (float*)(ws + Y0_BYTES + WT_BYTES);

  prep_kernel<<<144, 256, 0, stream>>>(conv_w, up2, dn2, wt, f1d);
  conv3x3_kernel<<<1024, 256, 0, stream>>>(x, wt, conv_b, bias, y0);
  upfirdn_kernel<<<8192, 256, 0, stream>>>(y0, f1d, outp);
}

// Round 2
// 284.751 us; speedup vs baseline: 1.0597x; 1.0597x over previous
//
#include <hip/hip_runtime.h>
#include <hip/hip_bf16.h>
#include <math.h>

// Problem constants
#define NB 8
#define CH 64
#define IN_SZ 128
#define PLANE (IN_SZ*IN_SZ)          // 16384

typedef __attribute__((ext_vector_type(8))) short short8;   // 8 bf16 = 4 VGPR
typedef __attribute__((ext_vector_type(4))) float f32x4;

// ws layout (bytes):
//   y0   : 8*64*128*128*4 = 33,554,432 @ 0
//   whi  : 9*64*64*2 = 73,728        @ Y0B           (layout [tap][co][ci], bf16)
//   wlo  : 73,728                    @ Y0B+WHB
//   bsum : 64*4                      @ Y0B+2*WHB     (conv_b + bias)
//   f1d  : 24*4                      @ Y0B+2*WHB+256 (up1d[12], dn1d[12])
#define Y0B   (NB*CH*PLANE*4)
#define WHB   (9*64*64*2)

// d_out scratch layout during prep/conv (dead before upfirdn writes output):
//   xhi_t : [8][128][128][64] bf16 = 16,777,216 B @ 0
//   xlo_t : same                                 @ 16,777,216 B

// ---------------------------------------------------------------------------
// prep_w: weights OIHW -> bf16 hi/lo [tap][co][ci]; bsum = conv_b + bias;
// separable 1-D filters from the 12x12 outer-product filters:
// f1d[k] = f2[k][5] / sqrt(f2[5][5]) (sign ambiguity cancels, applied per-dim).
// ---------------------------------------------------------------------------
__global__ __launch_bounds__(256) void prep_w_kernel(
    const float* __restrict__ w,     // [64][64][3][3]
    const float* __restrict__ cb,    // [64]
    const float* __restrict__ bias,  // [64]
    const float* __restrict__ up2,   // [12][12]
    const float* __restrict__ dn2,   // [12][12]
    __hip_bfloat16* __restrict__ whi,
    __hip_bfloat16* __restrict__ wlo,
    float* __restrict__ bsum,
    float* __restrict__ f1d) {
  int t = blockIdx.x * 256 + threadIdx.x;
  if (t < 9*64*64) {
    int tap = t >> 12;          // [tap][co][ci]
    int co  = (t >> 6) & 63;
    int ci  = t & 63;
    int ky = tap / 3, kx = tap % 3;
    float v = w[((co*64 + ci)*3 + ky)*3 + kx];
    __hip_bfloat16 h = __float2bfloat16(v);
    whi[t] = h;
    wlo[t] = __float2bfloat16(v - __bfloat162float(h));
  }
  if (blockIdx.x == 0) {
    if (threadIdx.x < 64) bsum[threadIdx.x] = cb[threadIdx.x] + bias[threadIdx.x];
    if (threadIdx.x >= 64 && threadIdx.x < 76) {
      int k = threadIdx.x - 64;
      f1d[k] = up2[k*12 + 5] / sqrtf(up2[5*12 + 5]);
    } else if (threadIdx.x >= 76 && threadIdx.x < 88) {
      int k = threadIdx.x - 76;
      f1d[12 + k] = dn2[k*12 + 5] / sqrtf(dn2[5*12 + 5]);
    }
  }
}

// ---------------------------------------------------------------------------
// prep_x: transpose + hi/lo split: x[b][ci][y][x] fp32 -> xhi_t/xlo_t
// [b][y][x][ci] bf16 (ci contiguous for 16B MFMA B-fragment loads).
// Block = (b, y): 1024 blocks. LDS tile transpose for coalescing both sides.
// ---------------------------------------------------------------------------
__global__ __launch_bounds__(256) void prep_x_kernel(
    const float* __restrict__ x,
    __hip_bfloat16* __restrict__ xhi,
    __hip_bfloat16* __restrict__ xlo) {
  __shared__ float tile[64][129];
  int blk = blockIdx.x;
  int y = blk & 127;
  int b = blk >> 7;
  int tid = threadIdx.x;
  // load: 2 ci-rows x 128 x per iteration (coalesced 512B per row)
  for (int i = 0; i < 32; ++i) {
    int idx = i*256 + tid;
    int ci = idx >> 7, xc = idx & 127;
    tile[ci][xc] = x[((size_t)(b*64 + ci)*128 + y)*128 + xc];
  }
  __syncthreads();
  // write: 4 x-cols x 64 ci per iteration (128B contiguous per wave)
  for (int i = 0; i < 32; ++i) {
    int idx = i*256 + tid;
    int xc = idx >> 6, ci = idx & 63;
    float v = tile[ci][xc];
    __hip_bfloat16 h = __float2bfloat16(v);
    size_t o = ((size_t)(b*128 + y)*128 + xc)*64 + ci;
    xhi[o] = h;
    xlo[o] = __float2bfloat16(v - __bfloat162float(h));
  }
}

// ---------------------------------------------------------------------------
// conv_mfma: implicit-GEMM 3x3 conv via mfma_f32_16x16x32_bf16, 3-product
// hi/lo split (Whi*Xhi + Wlo*Xhi in pass 0, Whi*Xlo in pass 1).
// Block = 256 thr = 4 waves; wave = one output row x 64 cols x all 64 co
// (4 co-tiles x 4 px-tiles = 16 accum frags). Grid: 8 b x 32 rowgroups x
// 2 colhalves = 512 blocks (2/CU).
// Fragment layouts (gfx950 16x16x32): A[m][k]: m=l%16, k=8*(l/16)+e;
// B[k][n]: n=l%16, k=8*(l/16)+e; D[r][c]: c=l%16, r=4*(l/16)+reg.
// ---------------------------------------------------------------------------
__global__ __launch_bounds__(256) void conv_mfma_kernel(
    const __hip_bfloat16* __restrict__ xhi,  // [8][128][128][64]
    const __hip_bfloat16* __restrict__ xlo,
    const __hip_bfloat16* __restrict__ whi,  // [9][64][64]
    const __hip_bfloat16* __restrict__ wlo,
    const float* __restrict__ bsum,          // [64]
    float* __restrict__ y0) {                // [8][64][128][128]
  int blk = blockIdx.x;
  int chf = blk & 1;
  int rg  = (blk >> 1) & 31;
  int b   = blk >> 6;
  int tid = threadIdx.x;
  int wv  = tid >> 6;
  int lane = tid & 63;
  int l16 = lane & 15;
  int g   = lane >> 4;
  int y   = rg*4 + wv;
  int px0 = chf*64;

  f32x4 acc[4][4];
#pragma unroll
  for (int ct = 0; ct < 4; ++ct) {
#pragma unroll
    for (int r = 0; r < 4; ++r) {
      float bv = bsum[ct*16 + g*4 + r];
#pragma unroll
      for (int pt = 0; pt < 4; ++pt) acc[ct][pt][r] = bv;
    }
  }

  const short8* WH = (const short8*)whi;
  const short8* WL = (const short8*)wlo;

  for (int pass = 0; pass < 2; ++pass) {
    const __hip_bfloat16* Xp = pass ? xlo : xhi;
    for (int tap = 0; tap < 9; ++tap) {
      int dy = tap / 3 - 1, dx = tap % 3 - 1;
      int ry = y + dy;
      if ((unsigned)ry >= 128u) continue;          // wave-uniform
      const __hip_bfloat16* xrow = Xp + ((size_t)(b*128 + ry)*128)*64;
      for (int cih = 0; cih < 2; ++cih) {
        short8 xb[4];
#pragma unroll
        for (int pt = 0; pt < 4; ++pt) {
          int col = px0 + pt*16 + l16 + dx;
          bool ok = (unsigned)col < 128u;
          int colc = col < 0 ? 0 : (col > 127 ? 127 : col);
          short8 v = *(const short8*)(xrow + (size_t)colc*64 + cih*32 + g*8);
          short8 zv = {0,0,0,0,0,0,0,0};
          xb[pt] = ok ? v : zv;
        }
        int wbase = (tap*64 + l16)*64 + cih*32 + g*8;  // element index
        if (pass == 0) {
#pragma unroll
          for (int ct = 0; ct < 4; ++ct) {
            short8 wh = WH[(wbase + ct*1024) >> 3];
            short8 wl = WL[(wbase + ct*1024) >> 3];
#pragma unroll
            for (int pt = 0; pt < 4; ++pt) {
              acc[ct][pt] = __builtin_amdgcn_mfma_f32_16x16x32_bf16(wh, xb[pt], acc[ct][pt], 0, 0, 0);
              acc[ct][pt] = __builtin_amdgcn_mfma_f32_16x16x32_bf16(wl, xb[pt], acc[ct][pt], 0, 0, 0);
            }
          }
        } else {
#pragma unroll
          for (int ct = 0; ct < 4; ++ct) {
            short8 wh = WH[(wbase + ct*1024) >> 3];
#pragma unroll
            for (int pt = 0; pt < 4; ++pt)
              acc[ct][pt] = __builtin_amdgcn_mfma_f32_16x16x32_bf16(wh, xb[pt], acc[ct][pt], 0, 0, 0);
          }
        }
      }
    }
  }

  // store: co = ct*16 + 4*g + r, px = px0 + pt*16 + l16
  float* yb = y0 + (size_t)b*64*PLANE + y*128 + px0;
#pragma unroll
  for (int ct = 0; ct < 4; ++ct)
#pragma unroll
    for (int pt = 0; pt < 4; ++pt)
#pragma unroll
      for (int r = 0; r < 4; ++r) {
        int co = ct*16 + g*4 + r;
        yb[(size_t)co*PLANE + pt*16 + l16] = acc[ct][pt][r];
      }
}

// ---------------------------------------------------------------------------
// upfirdn: fused repeat(2x) -> conv(up 12x12) -> lrelu*gain -> conv(dn 12x12)
//          -> ::2 downsample, separable filters, per 32x32-output tile.
// (unchanged from R1 — verified correct)
// ---------------------------------------------------------------------------
__global__ __launch_bounds__(256) void upfirdn_kernel(
    const float* __restrict__ y0,    // [512][128][128]
    const float* __restrict__ f1d,   // [24]
    float* __restrict__ out) {       // [512][128][128]
  __shared__ float ylds[43*44];
  __shared__ float Hlds[44*76];
  __shared__ float zlds[74*76];
  __shared__ float dhlds[74*32];

  int tid   = threadIdx.x;
  int blk   = blockIdx.x;
  int tile  = blk & 15;
  int plane = blk >> 4;
  int ty = tile >> 2, tx = tile & 3;
  int i0 = ty*32, j0 = tx*32;
  const float* yp = y0 + (size_t)plane*PLANE;

  float up1[12], dn1[12];
#pragma unroll
  for (int k = 0; k < 12; ++k) { up1[k] = f1d[k]; dn1[k] = f1d[12+k]; }

  for (int p = tid; p < 43*43; p += 256) {
    int r = p / 43, c = p - r*43;
    int gy = i0 - 5 + r, gx = j0 - 5 + c;
    float v = 0.f;
    if (((unsigned)gy < 128u) && ((unsigned)gx < 128u)) v = yp[gy*IN_SZ + gx];
    ylds[r*44 + c] = v;
  }
  __syncthreads();

  for (int p = tid; p < 43*19; p += 256) {
    int m = p / 19, G = p - m*19;
    const float* yr = &ylds[m*44 + 2*G];
    float4 ya = *(const float4*)(yr);
    float4 yb = *(const float4*)(yr + 4);
    float yreg[8] = {ya.x, ya.y, ya.z, ya.w, yb.x, yb.y, yb.z, yb.w};
    float hv[4];
#pragma unroll
    for (int s = 0; s < 4; ++s) {
      float a = 0.f;
#pragma unroll
      for (int k = 0; k < 12; ++k) a += up1[k] * yreg[(s+k) >> 1];
      hv[s] = a;
    }
    int qxi0 = 4*G;
    float* hp = &Hlds[m*76 + qxi0];
    if (qxi0 < 72) {
      *(float4*)hp = make_float4(hv[0], hv[1], hv[2], hv[3]);
    } else {
      hp[0] = hv[0]; hp[1] = hv[1];
    }
  }
  __syncthreads();

  int Qy0 = 2*i0 - 5, Qx0 = 2*j0 - 5;
  for (int p = tid; p < 19*74; p += 256) {
    int g = p / 74, qxi = p - g*74;
    float hreg[8];
#pragma unroll
    for (int r = 0; r < 8; ++r) hreg[r] = Hlds[(2*g + r)*76 + qxi];
    int qx = Qx0 + qxi;
    bool xok = ((unsigned)qx < 256u);
#pragma unroll
    for (int s = 0; s < 4; ++s) {
      int qyi = 4*g + s;
      if (qyi < 74) {
        float a = 0.f;
#pragma unroll
        for (int k = 0; k < 12; ++k) a += up1[k] * hreg[(s+k) >> 1];
        a = (a >= 0.f ? a : 0.2f*a) * 1.4142135623730951f;
        int qy = Qy0 + qyi;
        bool ok = xok && ((unsigned)qy < 256u);
        zlds[qyi*76 + qxi] = ok ? a : 0.f;
      }
    }
  }
  __syncthreads();

  for (int p = tid; p < 74*8; p += 256) {
    int qyi = p >> 3, gj = p & 7;
    const float* zr = &zlds[qyi*76 + 8*gj];
    float4 z0 = *(const float4*)(zr);
    float4 z1 = *(const float4*)(zr + 4);
    float4 z2 = *(const float4*)(zr + 8);
    float4 z3 = *(const float4*)(zr + 12);
    float2 z4 = *(const float2*)(zr + 16);
    float zreg[18] = {z0.x,z0.y,z0.z,z0.w, z1.x,z1.y,z1.z,z1.w,
                      z2.x,z2.y,z2.z,z2.w, z3.x,z3.y,z3.z,z3.w, z4.x,z4.y};
#pragma unroll
    for (int s = 0; s < 4; ++s) {
      float a = 0.f;
#pragma unroll
      for (int k = 0; k < 12; ++k) a += dn1[k] * zreg[2*s + k];
      dhlds[qyi*32 + 4*gj + s] = a;
    }
  }
  __syncthreads();

  {
    int p = tid;
    int gi = p >> 5, j = p & 31;
    float dreg[18];
#pragma unroll
    for (int r = 0; r < 18; ++r) dreg[r] = dhlds[(8*gi + r)*32 + j];
    float* op = out + (size_t)plane*PLANE + (i0 + 4*gi)*IN_SZ + (j0 + j);
#pragma unroll
    for (int s = 0; s < 4; ++s) {
      float a = 0.f;
#pragma unroll
      for (int k = 0; k < 12; ++k) a += dn1[k] * dreg[2*s + k];
      op[s*IN_SZ] = a;
    }
  }
}

// ---------------------------------------------------------------------------
extern "C" void kernel_launch(void* const* d_in, const int* in_sizes, int n_in,
                              void* d_out, int out_size, void* d_ws, size_t ws_size,
                              hipStream_t stream) {
  const float* x      = (const float*)d_in[0];
  const float* conv_w = (const float*)d_in[1];
  const float* conv_b = (const float*)d_in[2];
  const float* bias   = (const float*)d_in[3];
  const float* up2    = (const float*)d_in[4];
  const float* dn2    = (const float*)d_in[5];
  float* outp = (float*)d_out;

  char* ws = (char*)d_ws;
  float* y0  = (float*)(ws);
  __hip_bfloat16* whi = (__hip_bfloat16*)(ws + Y0B);
  __hip_bfloat16* wlo = (__hip_bfloat16*)(ws + Y0B + WHB);
  float* bsum = (float*)(ws + Y0B + 2*WHB);
  float* f1d  = (float*)(ws + Y0B + 2*WHB + 256);

  // x hi/lo planes live in d_out as scratch (exactly 2 x 16.78MB = out bytes);
  // dead before upfirdn writes the real output.
  __hip_bfloat16* xhi = (__hip_bfloat16*)d_out;
  __hip_bfloat16* xlo = xhi + (size_t)NB*PLANE*64;

  prep_w_kernel<<<144, 256, 0, stream>>>(conv_w, conv_b, bias, up2, dn2, whi, wlo, bsum, f1d);
  prep_x_kernel<<<1024, 256, 0, stream>>>(x, xhi, xlo);
  conv_mfma_kernel<<<512, 256, 0, stream>>>(xhi, xlo, whi, wlo, bsum, y0);
  upfirdn_kernel<<<8192, 256, 0, stream>>>(y0, f1d, outp);
}

// Round 3
// 259.543 us; speedup vs baseline: 1.1626x; 1.0971x over previous
//
#include <hip/hip_runtime.h>
#include <hip/hip_bf16.h>
#include <math.h>

// Problem constants
#define NB 8
#define CH 64
#define IN_SZ 128
#define PLANE (IN_SZ*IN_SZ)          // 16384

typedef __attribute__((ext_vector_type(8))) short short8;   // 8 bf16 = 4 VGPR
typedef __attribute__((ext_vector_type(4))) float f32x4;

// ws layout (bytes):
//   y0   : 8*64*128*128*4 = 33,554,432 @ 0
//   whi  : 9*64*64*2 = 73,728        @ Y0B           ([tap][co][ci], bf16)
//   wlo  : 73,728                    @ Y0B+WHB
//   bsum : 64*4                      @ Y0B+2*WHB     (conv_b + bias)
//   f1d  : 25*4                      @ Y0B+2*WHB+256 (e[6], o[7], dn[12])
#define Y0B   (NB*CH*PLANE*4)
#define WHB   (9*64*64*2)

// d_out scratch during prep/conv (dead before upfirdn writes output):
//   xhi_t : [8][128][128][64] bf16 @ 0 ; xlo_t same @ +16,777,216 B

// ---------------------------------------------------------------------------
// prep_w: weights OIHW -> bf16 hi/lo [tap][co][ci]; bsum = conv_b + bias;
// POLYPHASE 1-D filters from the separable 12x12 outer products:
//   u[k] = up2[k][5]/sqrt(up2[5][5])   (sign ambiguity cancels per-dim)
//   e[j] = u[2j]+u[2j+1] (even phase, 6 taps)
//   o[0]=u[0]; o[j]=u[2j-1]+u[2j] (j=1..5); o[6]=u[11] (odd phase, 7 taps)
//   dn[k] as before (decimation: no polyphase sharing).
// ---------------------------------------------------------------------------
__global__ __launch_bounds__(256) void prep_w_kernel(
    const float* __restrict__ w,     // [64][64][3][3]
    const float* __restrict__ cb,    // [64]
    const float* __restrict__ bias,  // [64]
    const float* __restrict__ up2,   // [12][12]
    const float* __restrict__ dn2,   // [12][12]
    __hip_bfloat16* __restrict__ whi,
    __hip_bfloat16* __restrict__ wlo,
    float* __restrict__ bsum,
    float* __restrict__ f1d) {
  int t = blockIdx.x * 256 + threadIdx.x;
  if (t < 9*64*64) {
    int tap = t >> 12;          // [tap][co][ci]
    int co  = (t >> 6) & 63;
    int ci  = t & 63;
    int ky = tap / 3, kx = tap % 3;
    float v = w[((co*64 + ci)*3 + ky)*3 + kx];
    __hip_bfloat16 h = __float2bfloat16(v);
    whi[t] = h;
    wlo[t] = __float2bfloat16(v - __bfloat162float(h));
  }
  if (blockIdx.x == 0) {
    int tid = threadIdx.x;
    if (tid < 64) bsum[tid] = cb[tid] + bias[tid];
    float us = sqrtf(up2[5*12 + 5]);
    float ds = sqrtf(dn2[5*12 + 5]);
    if (tid >= 64 && tid < 70) {          // e[6]
      int j = tid - 64;
      f1d[j] = (up2[(2*j)*12 + 5] + up2[(2*j + 1)*12 + 5]) / us;
    } else if (tid >= 70 && tid < 77) {   // o[7]
      int j = tid - 70;
      float v;
      if (j == 0)      v = up2[0*12 + 5];
      else if (j == 6) v = up2[11*12 + 5];
      else             v = up2[(2*j - 1)*12 + 5] + up2[(2*j)*12 + 5];
      f1d[6 + j] = v / us;
    } else if (tid >= 77 && tid < 89) {   // dn[12]
      int k = tid - 77;
      f1d[13 + k] = dn2[k*12 + 5] / ds;
    }
  }
}

// ---------------------------------------------------------------------------
// prep_x: transpose + hi/lo split: x[b][ci][y][x] fp32 -> xhi_t/xlo_t
// [b][y][x][ci] bf16. Packed 2-ci-per-lane uint stores (4B/lane, coalesced).
// ---------------------------------------------------------------------------
__global__ __launch_bounds__(256) void prep_x_kernel(
    const float* __restrict__ x,
    __hip_bfloat16* __restrict__ xhi,
    __hip_bfloat16* __restrict__ xlo) {
  __shared__ float tile[64][129];
  int blk = blockIdx.x;
  int y = blk & 127;
  int b = blk >> 7;
  int tid = threadIdx.x;
  for (int i = 0; i < 32; ++i) {
    int idx = i*256 + tid;
    int ci = idx >> 7, xc = idx & 127;
    tile[ci][xc] = x[((size_t)(b*64 + ci)*128 + y)*128 + xc];
  }
  __syncthreads();
  unsigned* oh = (unsigned*)xhi;
  unsigned* ol = (unsigned*)xlo;
  for (int i = 0; i < 16; ++i) {
    int idx = i*256 + tid;
    int xc = idx >> 5, cp = idx & 31;          // ci pair = 2*cp
    float v0 = tile[2*cp][xc];
    float v1 = tile[2*cp + 1][xc];
    __hip_bfloat16 h0 = __float2bfloat16(v0);
    __hip_bfloat16 h1 = __float2bfloat16(v1);
    __hip_bfloat16 l0 = __float2bfloat16(v0 - __bfloat162float(h0));
    __hip_bfloat16 l1 = __float2bfloat16(v1 - __bfloat162float(h1));
    unsigned uh = (unsigned)*(unsigned short*)&h0 | ((unsigned)*(unsigned short*)&h1 << 16);
    unsigned ul = (unsigned)*(unsigned short*)&l0 | ((unsigned)*(unsigned short*)&l1 << 16);
    size_t o = ((size_t)(b*128 + y)*128 + xc)*32 + cp;
    oh[o] = uh;
    ol[o] = ul;
  }
}

// ---------------------------------------------------------------------------
// conv_mfma: implicit-GEMM 3x3 conv via mfma_f32_16x16x32_bf16, 3-product
// hi/lo split (Whi*Xhi + Wlo*Xhi + Whi*Xlo), passes fused per tap.
// Wave = one row x 32 cols x 64 co: 4 co-tiles x 2 px-tiles = 8 acc frags.
// Grid: 8b x 32 rowgroups x 4 colquarters = 1024 blocks x 4 waves
// -> 4096 waves, 16 waves/CU (4/SIMD) for latency hiding.
// ---------------------------------------------------------------------------
__global__ __launch_bounds__(256, 4) void conv_mfma_kernel(
    const __hip_bfloat16* __restrict__ xhi,  // [8][128][128][64]
    const __hip_bfloat16* __restrict__ xlo,
    const __hip_bfloat16* __restrict__ whi,  // [9][64][64]
    const __hip_bfloat16* __restrict__ wlo,
    const float* __restrict__ bsum,          // [64]
    float* __restrict__ y0) {                // [8][64][128][128]
  int blk = blockIdx.x;
  int chq = blk & 3;
  int rg  = (blk >> 2) & 31;
  int b   = blk >> 7;
  int tid = threadIdx.x;
  int wv  = tid >> 6;
  int lane = tid & 63;
  int l16 = lane & 15;
  int g   = lane >> 4;
  int y   = rg*4 + wv;
  int px0 = chq*32;

  f32x4 acc[4][2];
#pragma unroll
  for (int ct = 0; ct < 4; ++ct) {
#pragma unroll
    for (int r = 0; r < 4; ++r) {
      float bv = bsum[ct*16 + g*4 + r];
#pragma unroll
      for (int pt = 0; pt < 2; ++pt) acc[ct][pt][r] = bv;
    }
  }

  const short8* WH = (const short8*)whi;
  const short8* WL = (const short8*)wlo;
  const short8 zv8 = {0,0,0,0,0,0,0,0};

  for (int tap = 0; tap < 9; ++tap) {
    int dy = tap / 3 - 1, dx = tap % 3 - 1;
    int ry = y + dy;
    if ((unsigned)ry >= 128u) continue;          // wave-uniform
    const __hip_bfloat16* rh = xhi + ((size_t)(b*128 + ry)*128)*64;
    const __hip_bfloat16* rl = xlo + ((size_t)(b*128 + ry)*128)*64;
#pragma unroll
    for (int cih = 0; cih < 2; ++cih) {
      short8 xh[2], xl[2];
#pragma unroll
      for (int pt = 0; pt < 2; ++pt) {
        int col = px0 + pt*16 + l16 + dx;
        bool ok = (unsigned)col < 128u;
        int colc = col < 0 ? 0 : (col > 127 ? 127 : col);
        size_t off = (size_t)colc*64 + cih*32 + g*8;
        short8 vh = *(const short8*)(rh + off);
        short8 vl = *(const short8*)(rl + off);
        xh[pt] = ok ? vh : zv8;
        xl[pt] = ok ? vl : zv8;
      }
      int wbase = (tap*64 + l16)*64 + cih*32 + g*8;  // element index
#pragma unroll
      for (int ct = 0; ct < 4; ++ct) {
        short8 wh = WH[(wbase + ct*1024) >> 3];
        short8 wl = WL[(wbase + ct*1024) >> 3];
#pragma unroll
        for (int pt = 0; pt < 2; ++pt) {
          acc[ct][pt] = __builtin_amdgcn_mfma_f32_16x16x32_bf16(wh, xh[pt], acc[ct][pt], 0, 0, 0);
          acc[ct][pt] = __builtin_amdgcn_mfma_f32_16x16x32_bf16(wl, xh[pt], acc[ct][pt], 0, 0, 0);
          acc[ct][pt] = __builtin_amdgcn_mfma_f32_16x16x32_bf16(wh, xl[pt], acc[ct][pt], 0, 0, 0);
        }
      }
    }
  }

  // store: co = ct*16 + 4*g + r, px = px0 + pt*16 + l16
  float* yb = y0 + (size_t)b*64*PLANE + y*128 + px0;
#pragma unroll
  for (int ct = 0; ct < 4; ++ct)
#pragma unroll
    for (int pt = 0; pt < 2; ++pt)
#pragma unroll
      for (int r = 0; r < 4; ++r) {
        int co = ct*16 + g*4 + r;
        yb[(size_t)co*PLANE + pt*16 + l16] = acc[ct][pt][r];
      }
}

// ---------------------------------------------------------------------------
// upfirdn: fused repeat(2x) -> up-FIR -> lrelu*gain -> dn-FIR -> ::2,
// POLYPHASE up filters (e[6]/o[7]), tile = 32x64 outputs, 512 threads.
// LDS union (65,520 B -> 2 blocks/CU = 16 waves/CU):
//   Z  [0, 10360) floats, 74 rows x pitch 140   (phase 3 w, 4 r)
//   Y  [0, 3268)  ALIAS in Z (dead before Z written), 43 x pitch 76
//   H  [10360, 16380), 43 rows x pitch 140      (phase 2 w, 3 r)
//   DH [10360, 15096) ALIAS over H (dead), 74 rows x pitch 64
// Index math: H[m][qxi] = sum_j pf[j]*y[(qxi>>1)+j] (pf=e/o by parity of qxi);
// vertical identical; dn: out[i][j] = sum_k dn[k]*z[2i+k][2j+k'] separable.
// ---------------------------------------------------------------------------
#define ZOFF  0
#define YOFF  0
#define HOFF  10360
#define DHOFF 10360
#define ZP 140
#define HP 140
#define YP 76
#define DHP 64

__global__ __launch_bounds__(512, 4) void upfirdn_kernel(
    const float* __restrict__ y0,    // [512][128][128]
    const float* __restrict__ f1d,   // [25]: e[6], o[7], dn[12]
    float* __restrict__ out) {       // [512][128][128]
  __shared__ float lds[16380];

  int tid   = threadIdx.x;
  int blk   = blockIdx.x;
  int tile  = blk & 7;
  int plane = blk >> 3;
  int ty = tile >> 1, tx = tile & 1;
  int i0 = ty*32, j0 = tx*64;
  const float* yp = y0 + (size_t)plane*PLANE;

  float ef[6], of[7], dnf[12];
#pragma unroll
  for (int j = 0; j < 6; ++j) ef[j] = f1d[j];
#pragma unroll
  for (int j = 0; j < 7; ++j) of[j] = f1d[6 + j];
#pragma unroll
  for (int k = 0; k < 12; ++k) dnf[k] = f1d[13 + k];

  // phase 1: load y0 tile, zero-pad outside [0,128)^2. 43 rows x 76 cols.
  for (int p = tid; p < 43*76; p += 512) {
    int r = p / 76, c = p - r*76;
    int gy = i0 - 5 + r, gx = j0 - 5 + c;
    float v = 0.f;
    if (((unsigned)gy < 128u) && ((unsigned)gx < 128u)) v = yp[gy*IN_SZ + gx];
    lds[YOFF + r*YP + c] = v;
  }
  __syncthreads();

  // phase 2: horizontal up-pass, polyphase. H rows 0..42, cols 0..139
  // (cols >137 are pad-garbage, never read downstream). Group 4 qxi.
  for (int p = tid; p < 43*35; p += 512) {
    int m = p / 35, G = p - m*35;
    const float* yr = lds + YOFF + m*YP + 2*G;
    float4 ya = *(const float4*)(yr);
    float4 yb = *(const float4*)(yr + 4);
    float yreg[8] = {ya.x, ya.y, ya.z, ya.w, yb.x, yb.y, yb.z, yb.w};
    float hv[4];
#pragma unroll
    for (int s = 0; s < 4; ++s) {
      int base = s >> 1;
      float a = 0.f;
      if ((s & 1) == 0) {
#pragma unroll
        for (int j = 0; j < 6; ++j) a += ef[j]*yreg[base + j];
      } else {
#pragma unroll
        for (int j = 0; j < 7; ++j) a += of[j]*yreg[base + j];
      }
      hv[s] = a;
    }
    *(float4*)(lds + HOFF + m*HP + 4*G) = make_float4(hv[0], hv[1], hv[2], hv[3]);
  }
  __syncthreads();

  // phase 3: vertical up-pass + lrelu*gain + boundary zero -> Z.
  // 4x4 output groups, b128 H reads. Row clamp 42: row 43 only feeds
  // invalid outputs (qyi>=74), clamping keeps addresses in-bounds.
  int Qy0 = 2*i0 - 5, Qx0 = 2*j0 - 5;
  for (int p = tid; p < 19*35; p += 512) {
    int gq = p / 35, q = p - gq*35;
    f32x4 hreg[8];
#pragma unroll
    for (int r = 0; r < 8; ++r) {
      int hrow = 2*gq + r;
      if (hrow > 42) hrow = 42;
      hreg[r] = *(const f32x4*)(lds + HOFF + hrow*HP + 4*q);
    }
    int qx0 = Qx0 + 4*q;
#pragma unroll
    for (int s = 0; s < 4; ++s) {
      int qyi = 4*gq + s;
      if (qyi < 74) {
        int base = s >> 1;
        f32x4 a = {0.f, 0.f, 0.f, 0.f};
        if ((s & 1) == 0) {
#pragma unroll
          for (int j = 0; j < 6; ++j) a += ef[j]*hreg[base + j];
        } else {
#pragma unroll
          for (int j = 0; j < 7; ++j) a += of[j]*hreg[base + j];
        }
        bool yok = (unsigned)(Qy0 + qyi) < 256u;
        f32x4 zv;
#pragma unroll
        for (int t = 0; t < 4; ++t) {
          float av = a[t];
          av = (av >= 0.f ? av : 0.2f*av) * 1.4142135623730951f;
          bool ok = yok && ((unsigned)(qx0 + t) < 256u);
          zv[t] = ok ? av : 0.f;
        }
        *(f32x4*)(lds + ZOFF + qyi*ZP + 4*q) = zv;
      }
    }
  }
  __syncthreads();

  // phase 4: horizontal dn-pass at even output cols. dh[qyi][j], j grouped 4.
  for (int p = tid; p < 74*16; p += 512) {
    int qyi = p >> 4, gj = p & 15;
    const float* zr = lds + ZOFF + qyi*ZP + 8*gj;
    float4 z0 = *(const float4*)(zr);
    float4 z1 = *(const float4*)(zr + 4);
    float4 z2 = *(const float4*)(zr + 8);
    float4 z3 = *(const float4*)(zr + 12);
    float2 z4 = *(const float2*)(zr + 16);
    float zreg[18] = {z0.x,z0.y,z0.z,z0.w, z1.x,z1.y,z1.z,z1.w,
                      z2.x,z2.y,z2.z,z2.w, z3.x,z3.y,z3.z,z3.w, z4.x,z4.y};
    float dv[4];
#pragma unroll
    for (int s = 0; s < 4; ++s) {
      float a = 0.f;
#pragma unroll
      for (int k = 0; k < 12; ++k) a += dnf[k]*zreg[2*s + k];
      dv[s] = a;
    }
    *(float4*)(lds + DHOFF + qyi*DHP + 4*gj) = make_float4(dv[0], dv[1], dv[2], dv[3]);
  }
  __syncthreads();

  // phase 5: vertical dn-pass at even output rows, write result.
  {
    int gi = tid >> 6, j = tid & 63;
    float dreg[18];
#pragma unroll
    for (int r = 0; r < 18; ++r) dreg[r] = lds[DHOFF + (8*gi + r)*DHP + j];
    float* op = out + (size_t)plane*PLANE + (i0 + 4*gi)*IN_SZ + (j0 + j);
#pragma unroll
    for (int s = 0; s < 4; ++s) {
      float a = 0.f;
#pragma unroll
      for (int k = 0; k < 12; ++k) a += dnf[k]*dreg[2*s + k];
      op[s*IN_SZ] = a;
    }
  }
}

// ---------------------------------------------------------------------------
extern "C" void kernel_launch(void* const* d_in, const int* in_sizes, int n_in,
                              void* d_out, int out_size, void* d_ws, size_t ws_size,
                              hipStream_t stream) {
  const float* x      = (const float*)d_in[0];
  const float* conv_w = (const float*)d_in[1];
  const float* conv_b = (const float*)d_in[2];
  const float* bias   = (const float*)d_in[3];
  const float* up2    = (const float*)d_in[4];
  const float* dn2    = (const float*)d_in[5];
  float* outp = (float*)d_out;

  char* ws = (char*)d_ws;
  float* y0  = (float*)(ws);
  __hip_bfloat16* whi = (__hip_bfloat16*)(ws + Y0B);
  __hip_bfloat16* wlo = (__hip_bfloat16*)(ws + Y0B + WHB);
  float* bsum = (float*)(ws + Y0B + 2*WHB);
  float* f1d  = (float*)(ws + Y0B + 2*WHB + 256);

  // x hi/lo planes live in d_out as scratch (2 x 16.78MB = out bytes);
  // dead before upfirdn writes the real output.
  __hip_bfloat16* xhi = (__hip_bfloat16*)d_out;
  __hip_bfloat16* xlo = xhi + (size_t)NB*PLANE*64;

  prep_w_kernel<<<144, 256, 0, stream>>>(conv_w, conv_b, bias, up2, dn2, whi, wlo, bsum, f1d);
  prep_x_kernel<<<1024, 256, 0, stream>>>(x, xhi, xlo);
  conv_mfma_kernel<<<1024, 256, 0, stream>>>(xhi, xlo, whi, wlo, bsum, y0);
  upfirdn_kernel<<<4096, 512, 0, stream>>>(y0, f1d, outp);
}

// Round 4
// 192.583 us; speedup vs baseline: 1.5668x; 1.3477x over previous
//
#include <hip/hip_runtime.h>
#include <hip/hip_bf16.h>
#include <math.h>

// Problem constants
#define NB 8
#define CH 64
#define IN_SZ 128
#define PLANE (IN_SZ*IN_SZ)          // 16384

typedef __attribute__((ext_vector_type(8))) short short8;   // 8 bf16 = 4 VGPR
typedef __attribute__((ext_vector_type(4))) float f32x4;
typedef __attribute__((ext_vector_type(4))) int   int4v;

// ws layout (bytes):
//   y0   : 8*64*128*128*4 = 33,554,432 @ 0
//   whi  : 9*2*4*4*16*8*2 = 73,728    @ Y0B   ([tap][cih][ct][g][l16][8ci] bf16)
//   wlo  : 73,728                     @ Y0B+WHB
//   bsum : 64*4                       @ Y0B+2*WHB     (conv_b + bias)
//   f1d  : 25*4                       @ Y0B+2*WHB+256 (e[6], o[7], dn[12])
#define Y0B   (NB*CH*PLANE*4)
#define WHB   (9*64*64*2)

// d_out scratch during prep/conv (dead before upfirdn writes output):
//   xhi : [8][128][8xb][2cih][4g][16l][8ci] bf16 @ 0 ; xlo same @ +16,777,216 B

// ---------------------------------------------------------------------------
// DPP lane-shift helpers (within 16-lane rows; edge lane merged from the
// neighbor fragment). old=0 everywhere + OR-combine => result is identical
// under either bound_ctrl interpretation (invalid -> 0 or invalid -> old=0).
// ---------------------------------------------------------------------------
__device__ __forceinline__ short8 dpp_shift_p1(short8 a, short8 nb) {
  // dst[l16] = a[l16+1]; dst[15] = nb[0]
  int4v ai = __builtin_bit_cast(int4v, a);
  int4v ni = __builtin_bit_cast(int4v, nb);
  int4v r;
#pragma unroll
  for (int t = 0; t < 4; ++t) {
    int m = __builtin_amdgcn_update_dpp(0, ai[t], 0x101, 0xf, 0xf, true); // row_shl:1
    int n = __builtin_amdgcn_update_dpp(0, ni[t], 0x11F, 0xf, 0xf, true); // row_shr:15
    r[t] = m | n;
  }
  return __builtin_bit_cast(short8, r);
}
__device__ __forceinline__ short8 dpp_shift_m1(short8 a, short8 nb) {
  // dst[l16] = a[l16-1]; dst[0] = nb[15]
  int4v ai = __builtin_bit_cast(int4v, a);
  int4v ni = __builtin_bit_cast(int4v, nb);
  int4v r;
#pragma unroll
  for (int t = 0; t < 4; ++t) {
    int m = __builtin_amdgcn_update_dpp(0, ai[t], 0x111, 0xf, 0xf, true); // row_shr:1
    int n = __builtin_amdgcn_update_dpp(0, ni[t], 0x10F, 0xf, 0xf, true); // row_shl:15
    r[t] = m | n;
  }
  return __builtin_bit_cast(short8, r);
}

// ---------------------------------------------------------------------------
// prep_w: weights OIHW -> bf16 hi/lo MFMA-native [tap][cih][ct][g][l16][8ci];
// bsum = conv_b + bias; polyphase 1-D filters (e[6], o[7], dn[12]).
// ---------------------------------------------------------------------------
__global__ __launch_bounds__(256) void prep_w_kernel(
    const float* __restrict__ w,     // [64][64][3][3]
    const float* __restrict__ cb,    // [64]
    const float* __restrict__ bias,  // [64]
    const float* __restrict__ up2,   // [12][12]
    const float* __restrict__ dn2,   // [12][12]
    __hip_bfloat16* __restrict__ whi,
    __hip_bfloat16* __restrict__ wlo,
    float* __restrict__ bsum,
    float* __restrict__ f1d) {
  int t = blockIdx.x * 256 + threadIdx.x;
  if (t < 9*64*64) {
    int e   = t & 7;
    int l16 = (t >> 3) & 15;
    int g   = (t >> 7) & 3;
    int ct  = (t >> 9) & 3;
    int cih = (t >> 11) & 1;
    int tap = t >> 12;
    int co = ct*16 + l16;
    int ci = cih*32 + g*8 + e;
    int ky = tap / 3, kx = tap % 3;
    float v = w[((co*64 + ci)*3 + ky)*3 + kx];
    __hip_bfloat16 h = __float2bfloat16(v);
    whi[t] = h;
    wlo[t] = __float2bfloat16(v - __bfloat162float(h));
  }
  if (blockIdx.x == 0) {
    int tid = threadIdx.x;
    if (tid < 64) bsum[tid] = cb[tid] + bias[tid];
    float us = sqrtf(up2[5*12 + 5]);
    float ds = sqrtf(dn2[5*12 + 5]);
    if (tid >= 64 && tid < 70) {          // e[6]
      int j = tid - 64;
      f1d[j] = (up2[(2*j)*12 + 5] + up2[(2*j + 1)*12 + 5]) / us;
    } else if (tid >= 70 && tid < 77) {   // o[7]
      int j = tid - 70;
      float v;
      if (j == 0)      v = up2[0*12 + 5];
      else if (j == 6) v = up2[11*12 + 5];
      else             v = up2[(2*j - 1)*12 + 5] + up2[(2*j)*12 + 5];
      f1d[6 + j] = v / us;
    } else if (tid >= 77 && tid < 89) {   // dn[12]
      int k = tid - 77;
      f1d[13 + k] = dn2[k*12 + 5] / ds;
    }
  }
}

// ---------------------------------------------------------------------------
// prep_x: x[b][ci][y][x] fp32 -> MFMA-native bf16 hi/lo
// [b][y][xb][cih][g][l16][8ci]. One block per (b,y) row.
// ---------------------------------------------------------------------------
__global__ __launch_bounds__(256) void prep_x_kernel(
    const float* __restrict__ x,
    __hip_bfloat16* __restrict__ xhi,
    __hip_bfloat16* __restrict__ xlo) {
  __shared__ float tile[64][129];
  int blk = blockIdx.x;
  int y = blk & 127;
  int b = blk >> 7;
  int tid = threadIdx.x;
  for (int i = 0; i < 32; ++i) {
    int idx = i*256 + tid;
    int ci = idx >> 7, xc = idx & 127;
    tile[ci][xc] = x[((size_t)(b*64 + ci)*128 + y)*128 + xc];
  }
  __syncthreads();
  unsigned* oh = (unsigned*)xhi;
  unsigned* ol = (unsigned*)xlo;
  size_t rowu = (size_t)(b*128 + y)*4096;   // uints per row = 4096
  for (int i = 0; i < 16; ++i) {
    int u = i*256 + tid;                    // 0..4095
    int ep  = u & 3;
    int l16 = (u >> 2) & 15;
    int g   = (u >> 6) & 3;
    int cih = (u >> 8) & 1;
    int xb  = u >> 9;
    int ci0 = cih*32 + g*8 + ep*2;
    int xc  = xb*16 + l16;
    float v0 = tile[ci0][xc];
    float v1 = tile[ci0 + 1][xc];
    __hip_bfloat16 h0 = __float2bfloat16(v0);
    __hip_bfloat16 h1 = __float2bfloat16(v1);
    __hip_bfloat16 l0 = __float2bfloat16(v0 - __bfloat162float(h0));
    __hip_bfloat16 l1 = __float2bfloat16(v1 - __bfloat162float(h1));
    unsigned uh = (unsigned)*(unsigned short*)&h0 | ((unsigned)*(unsigned short*)&h1 << 16);
    unsigned ul = (unsigned)*(unsigned short*)&l0 | ((unsigned)*(unsigned short*)&l1 << 16);
    oh[rowu + u] = uh;
    ol[rowu + u] = ul;
  }
}

// ---------------------------------------------------------------------------
// conv_mfma v3: implicit-GEMM 3x3 conv, mfma_f32_16x16x32_bf16, 3-product
// hi/lo split. ALL global loads wave-contiguous (1KB/instr): x and w in
// MFMA-native layouts; the +-1 column taps are built in-register via DPP
// lane shifts (edge lane merged from the neighbor fragment).
// Wave = 1 row x 32 cols x 64 co (4ct x 2pt acc frags).
// Grid: 8b x 32rg x 4colq = 1024 blocks x 4 waves.
// ---------------------------------------------------------------------------
__global__ __launch_bounds__(256, 3) void conv_mfma_kernel(
    const __hip_bfloat16* __restrict__ xhi,  // [8][128][8][2][4][16][8]
    const __hip_bfloat16* __restrict__ xlo,
    const __hip_bfloat16* __restrict__ whi,  // [9][2][4][4][16][8]
    const __hip_bfloat16* __restrict__ wlo,
    const float* __restrict__ bsum,          // [64]
    float* __restrict__ y0) {                // [8][64][128][128]
  int blk = blockIdx.x;
  int colq = blk & 3;
  int rg  = (blk >> 2) & 31;
  int b   = blk >> 7;
  int tid = threadIdx.x;
  int wv  = tid >> 6;
  int lane = tid & 63;
  int l16 = lane & 15;
  int g   = lane >> 4;
  int y   = rg*4 + wv;
  int xb  = colq*2;
  int px0 = colq*32;

  f32x4 acc[4][2];
#pragma unroll
  for (int ct = 0; ct < 4; ++ct) {
#pragma unroll
    for (int r = 0; r < 4; ++r) {
      float bv = bsum[ct*16 + g*4 + r];
#pragma unroll
      for (int pt = 0; pt < 2; ++pt) acc[ct][pt][r] = bv;
    }
  }

  const short8 zv8 = {0,0,0,0,0,0,0,0};
  int lofs = (g*16 + l16)*8;                 // per-lane chunk offset (elements)

  for (int dy = -1; dy <= 1; ++dy) {
    int ry = y + dy;
    if ((unsigned)ry >= 128u) continue;      // wave-uniform
    const __hip_bfloat16* rh = xhi + (size_t)(b*128 + ry)*8192;
    const __hip_bfloat16* rl = xlo + (size_t)(b*128 + ry)*8192;
#pragma unroll
    for (int cih = 0; cih < 2; ++cih) {
      // aligned fragments for col-blocks xb-1 .. xb+2
      short8 Fh[4], Fl[4];
#pragma unroll
      for (int i = 0; i < 4; ++i) {
        int xbF = xb - 1 + i;
        if ((unsigned)xbF < 8u) {
          size_t off = (size_t)((xbF*2 + cih)*64)*8 + lofs;  // (xb*2+cih)*4g*16l*8e
          Fh[i] = *(const short8*)(rh + off);
          Fl[i] = *(const short8*)(rl + off);
        } else {
          Fh[i] = zv8; Fl[i] = zv8;
        }
      }
#pragma unroll
      for (int dxn = 0; dxn < 3; ++dxn) {    // dx = dxn-1
        int tap = (dy + 1)*3 + dxn;
        short8 xhf[2], xlf[2];
#pragma unroll
        for (int pt = 0; pt < 2; ++pt) {
          if (dxn == 1) { xhf[pt] = Fh[pt + 1]; xlf[pt] = Fl[pt + 1]; }
          else if (dxn == 2) {
            xhf[pt] = dpp_shift_p1(Fh[pt + 1], Fh[pt + 2]);
            xlf[pt] = dpp_shift_p1(Fl[pt + 1], Fl[pt + 2]);
          } else {
            xhf[pt] = dpp_shift_m1(Fh[pt + 1], Fh[pt]);
            xlf[pt] = dpp_shift_m1(Fl[pt + 1], Fl[pt]);
          }
        }
        const __hip_bfloat16* wb = whi + (size_t)((tap*2 + cih)*4)*512;
        const __hip_bfloat16* wlb = wlo + (size_t)((tap*2 + cih)*4)*512;
#pragma unroll
        for (int ct = 0; ct < 4; ++ct) {
          short8 wh = *(const short8*)(wb  + (size_t)ct*512 + lofs);
          short8 wl = *(const short8*)(wlb + (size_t)ct*512 + lofs);
#pragma unroll
          for (int pt = 0; pt < 2; ++pt) {
            acc[ct][pt] = __builtin_amdgcn_mfma_f32_16x16x32_bf16(wh, xhf[pt], acc[ct][pt], 0, 0, 0);
            acc[ct][pt] = __builtin_amdgcn_mfma_f32_16x16x32_bf16(wl, xhf[pt], acc[ct][pt], 0, 0, 0);
            acc[ct][pt] = __builtin_amdgcn_mfma_f32_16x16x32_bf16(wh, xlf[pt], acc[ct][pt], 0, 0, 0);
          }
        }
      }
    }
  }

  // store: co = ct*16 + 4*g + r, px = px0 + pt*16 + l16
  float* yb = y0 + (size_t)b*64*PLANE + y*128 + px0;
#pragma unroll
  for (int ct = 0; ct < 4; ++ct)
#pragma unroll
    for (int pt = 0; pt < 2; ++pt)
#pragma unroll
      for (int r = 0; r < 4; ++r) {
        int co = ct*16 + g*4 + r;
        yb[(size_t)co*PLANE + pt*16 + l16] = acc[ct][pt][r];
      }
}

// ---------------------------------------------------------------------------
// upfirdn: fused repeat(2x) -> up-FIR -> lrelu*gain -> dn-FIR -> ::2,
// POLYPHASE up filters (e[6]/o[7]), tile = 32x64 outputs, 512 threads.
// (unchanged from R3 — verified correct)
// ---------------------------------------------------------------------------
#define ZOFF  0
#define YOFF  0
#define HOFF  10360
#define DHOFF 10360
#define ZP 140
#define HP 140
#define YP 76
#define DHP 64

__global__ __launch_bounds__(512, 4) void upfirdn_kernel(
    const float* __restrict__ y0,    // [512][128][128]
    const float* __restrict__ f1d,   // [25]: e[6], o[7], dn[12]
    float* __restrict__ out) {       // [512][128][128]
  __shared__ float lds[16380];

  int tid   = threadIdx.x;
  int blk   = blockIdx.x;
  int tile  = blk & 7;
  int plane = blk >> 3;
  int ty = tile >> 1, tx = tile & 1;
  int i0 = ty*32, j0 = tx*64;
  const float* yp = y0 + (size_t)plane*PLANE;

  float ef[6], of[7], dnf[12];
#pragma unroll
  for (int j = 0; j < 6; ++j) ef[j] = f1d[j];
#pragma unroll
  for (int j = 0; j < 7; ++j) of[j] = f1d[6 + j];
#pragma unroll
  for (int k = 0; k < 12; ++k) dnf[k] = f1d[13 + k];

  for (int p = tid; p < 43*76; p += 512) {
    int r = p / 76, c = p - r*76;
    int gy = i0 - 5 + r, gx = j0 - 5 + c;
    float v = 0.f;
    if (((unsigned)gy < 128u) && ((unsigned)gx < 128u)) v = yp[gy*IN_SZ + gx];
    lds[YOFF + r*YP + c] = v;
  }
  __syncthreads();

  for (int p = tid; p < 43*35; p += 512) {
    int m = p / 35, G = p - m*35;
    const float* yr = lds + YOFF + m*YP + 2*G;
    float4 ya = *(const float4*)(yr);
    float4 yb = *(const float4*)(yr + 4);
    float yreg[8] = {ya.x, ya.y, ya.z, ya.w, yb.x, yb.y, yb.z, yb.w};
    float hv[4];
#pragma unroll
    for (int s = 0; s < 4; ++s) {
      int base = s >> 1;
      float a = 0.f;
      if ((s & 1) == 0) {
#pragma unroll
        for (int j = 0; j < 6; ++j) a += ef[j]*yreg[base + j];
      } else {
#pragma unroll
        for (int j = 0; j < 7; ++j) a += of[j]*yreg[base + j];
      }
      hv[s] = a;
    }
    *(float4*)(lds + HOFF + m*HP + 4*G) = make_float4(hv[0], hv[1], hv[2], hv[3]);
  }
  __syncthreads();

  int Qy0 = 2*i0 - 5, Qx0 = 2*j0 - 5;
  for (int p = tid; p < 19*35; p += 512) {
    int gq = p / 35, q = p - gq*35;
    f32x4 hreg[8];
#pragma unroll
    for (int r = 0; r < 8; ++r) {
      int hrow = 2*gq + r;
      if (hrow > 42) hrow = 42;
      hreg[r] = *(const f32x4*)(lds + HOFF + hrow*HP + 4*q);
    }
    int qx0 = Qx0 + 4*q;
#pragma unroll
    for (int s = 0; s < 4; ++s) {
      int qyi = 4*gq + s;
      if (qyi < 74) {
        int base = s >> 1;
        f32x4 a = {0.f, 0.f, 0.f, 0.f};
        if ((s & 1) == 0) {
#pragma unroll
          for (int j = 0; j < 6; ++j) a += ef[j]*hreg[base + j];
        } else {
#pragma unroll
          for (int j = 0; j < 7; ++j) a += of[j]*hreg[base + j];
        }
        bool yok = (unsigned)(Qy0 + qyi) < 256u;
        f32x4 zv;
#pragma unroll
        for (int t = 0; t < 4; ++t) {
          float av = a[t];
          av = (av >= 0.f ? av : 0.2f*av) * 1.4142135623730951f;
          bool ok = yok && ((unsigned)(qx0 + t) < 256u);
          zv[t] = ok ? av : 0.f;
        }
        *(f32x4*)(lds + ZOFF + qyi*ZP + 4*q) = zv;
      }
    }
  }
  __syncthreads();

  for (int p = tid; p < 74*16; p += 512) {
    int qyi = p >> 4, gj = p & 15;
    const float* zr = lds + ZOFF + qyi*ZP + 8*gj;
    float4 z0 = *(const float4*)(zr);
    float4 z1 = *(const float4*)(zr + 4);
    float4 z2 = *(const float4*)(zr + 8);
    float4 z3 = *(const float4*)(zr + 12);
    float2 z4 = *(const float2*)(zr + 16);
    float zreg[18] = {z0.x,z0.y,z0.z,z0.w, z1.x,z1.y,z1.z,z1.w,
                      z2.x,z2.y,z2.z,z2.w, z3.x,z3.y,z3.z,z3.w, z4.x,z4.y};
    float dv[4];
#pragma unroll
    for (int s = 0; s < 4; ++s) {
      float a = 0.f;
#pragma unroll
      for (int k = 0; k < 12; ++k) a += dnf[k]*zreg[2*s + k];
      dv[s] = a;
    }
    *(float4*)(lds + DHOFF + qyi*DHP + 4*gj) = make_float4(dv[0], dv[1], dv[2], dv[3]);
  }
  __syncthreads();

  {
    int gi = tid >> 6, j = tid & 63;
    float dreg[18];
#pragma unroll
    for (int r = 0; r < 18; ++r) dreg[r] = lds[DHOFF + (8*gi + r)*DHP + j];
    float* op = out + (size_t)plane*PLANE + (i0 + 4*gi)*IN_SZ + (j0 + j);
#pragma unroll
    for (int s = 0; s < 4; ++s) {
      float a = 0.f;
#pragma unroll
      for (int k = 0; k < 12; ++k) a += dnf[k]*dreg[2*s + k];
      op[s*IN_SZ] = a;
    }
  }
}

// ---------------------------------------------------------------------------
extern "C" void kernel_launch(void* const* d_in, const int* in_sizes, int n_in,
                              void* d_out, int out_size, void* d_ws, size_t ws_size,
                              hipStream_t stream) {
  const float* x      = (const float*)d_in[0];
  const float* conv_w = (const float*)d_in[1];
  const float* conv_b = (const float*)d_in[2];
  const float* bias   = (const float*)d_in[3];
  const float* up2    = (const float*)d_in[4];
  const float* dn2    = (const float*)d_in[5];
  float* outp = (float*)d_out;

  char* ws = (char*)d_ws;
  float* y0  = (float*)(ws);
  __hip_bfloat16* whi = (__hip_bfloat16*)(ws + Y0B);
  __hip_bfloat16* wlo = (__hip_bfloat16*)(ws + Y0B + WHB);
  float* bsum = (float*)(ws + Y0B + 2*WHB);
  float* f1d  = (float*)(ws + Y0B + 2*WHB + 256);

  // x hi/lo planes live in d_out as scratch (2 x 16.78MB = out bytes);
  // dead before upfirdn writes the real output.
  __hip_bfloat16* xhi = (__hip_bfloat16*)d_out;
  __hip_bfloat16* xlo = xhi + (size_t)NB*PLANE*64;

  prep_w_kernel<<<144, 256, 0, stream>>>(conv_w, conv_b, bias, up2, dn2, whi, wlo, bsum, f1d);
  prep_x_kernel<<<1024, 256, 0, stream>>>(x, xhi, xlo);
  conv_mfma_kernel<<<1024, 256, 0, stream>>>(xhi, xlo, whi, wlo, bsum, y0);
  upfirdn_kernel<<<4096, 512, 0, stream>>>(y0, f1d, outp);
}

// Round 5
// 186.549 us; speedup vs baseline: 1.6175x; 1.0323x over previous
//
#include <hip/hip_runtime.h>
#include <hip/hip_bf16.h>
#include <math.h>

// Problem constants
#define NB 8
#define CH 64
#define IN_SZ 128
#define PLANE (IN_SZ*IN_SZ)          // 16384

typedef __attribute__((ext_vector_type(8))) short short8;   // 8 bf16 = 4 VGPR
typedef __attribute__((ext_vector_type(4))) float f32x4;
typedef __attribute__((ext_vector_type(4))) int   int4v;
typedef __attribute__((ext_vector_type(4))) unsigned uint4v;

// ws layout (bytes):
//   y0   : 8*64*128*128*4 = 33,554,432 @ 0
//   whi  : 9*2*4*4*16*8*2 = 73,728    @ Y0B   ([tap][cih][ct][g][l16][8ci] bf16)
//   wlo  : 73,728                     @ Y0B+WHB
//   bsum : 64*4                       @ Y0B+2*WHB     (conv_b + bias)
//   f1d  : 25*4                       @ Y0B+2*WHB+256 (e[6], o[7], dn[12])
#define Y0B   (NB*CH*PLANE*4)
#define WHB   (9*64*64*2)

// d_out scratch during prep/conv (dead before upfirdn writes output):
//   xhi : [8][128][8xb][2cih][4g][16l][8ci] bf16 @ 0 ; xlo same @ +16,777,216 B

// ---------------------------------------------------------------------------
// DPP lane-shift helpers (verified R4). Within 16-lane rows; edge lane merged
// from the neighbor fragment. old=0 + OR-combine.
// ---------------------------------------------------------------------------
__device__ __forceinline__ short8 dpp_shift_p1(short8 a, short8 nb) {
  int4v ai = __builtin_bit_cast(int4v, a);
  int4v ni = __builtin_bit_cast(int4v, nb);
  int4v r;
#pragma unroll
  for (int t = 0; t < 4; ++t) {
    int m = __builtin_amdgcn_update_dpp(0, ai[t], 0x101, 0xf, 0xf, true); // row_shl:1
    int n = __builtin_amdgcn_update_dpp(0, ni[t], 0x11F, 0xf, 0xf, true); // row_shr:15
    r[t] = m | n;
  }
  return __builtin_bit_cast(short8, r);
}
__device__ __forceinline__ short8 dpp_shift_m1(short8 a, short8 nb) {
  int4v ai = __builtin_bit_cast(int4v, a);
  int4v ni = __builtin_bit_cast(int4v, nb);
  int4v r;
#pragma unroll
  for (int t = 0; t < 4; ++t) {
    int m = __builtin_amdgcn_update_dpp(0, ai[t], 0x111, 0xf, 0xf, true); // row_shr:1
    int n = __builtin_amdgcn_update_dpp(0, ni[t], 0x10F, 0xf, 0xf, true); // row_shl:15
    r[t] = m | n;
  }
  return __builtin_bit_cast(short8, r);
}

// ---------------------------------------------------------------------------
// prep_w (unchanged from R4, verified)
// ---------------------------------------------------------------------------
__global__ __launch_bounds__(256) void prep_w_kernel(
    const float* __restrict__ w,     // [64][64][3][3]
    const float* __restrict__ cb,    // [64]
    const float* __restrict__ bias,  // [64]
    const float* __restrict__ up2,   // [12][12]
    const float* __restrict__ dn2,   // [12][12]
    __hip_bfloat16* __restrict__ whi,
    __hip_bfloat16* __restrict__ wlo,
    float* __restrict__ bsum,
    float* __restrict__ f1d) {
  int t = blockIdx.x * 256 + threadIdx.x;
  if (t < 9*64*64) {
    int e   = t & 7;
    int l16 = (t >> 3) & 15;
    int g   = (t >> 7) & 3;
    int ct  = (t >> 9) & 3;
    int cih = (t >> 11) & 1;
    int tap = t >> 12;
    int co = ct*16 + l16;
    int ci = cih*32 + g*8 + e;
    int ky = tap / 3, kx = tap % 3;
    float v = w[((co*64 + ci)*3 + ky)*3 + kx];
    __hip_bfloat16 h = __float2bfloat16(v);
    whi[t] = h;
    wlo[t] = __float2bfloat16(v - __bfloat162float(h));
  }
  if (blockIdx.x == 0) {
    int tid = threadIdx.x;
    if (tid < 64) bsum[tid] = cb[tid] + bias[tid];
    float us = sqrtf(up2[5*12 + 5]);
    float ds = sqrtf(dn2[5*12 + 5]);
    if (tid >= 64 && tid < 70) {          // e[6]
      int j = tid - 64;
      f1d[j] = (up2[(2*j)*12 + 5] + up2[(2*j + 1)*12 + 5]) / us;
    } else if (tid >= 70 && tid < 77) {   // o[7]
      int j = tid - 70;
      float v;
      if (j == 0)      v = up2[0*12 + 5];
      else if (j == 6) v = up2[11*12 + 5];
      else             v = up2[(2*j - 1)*12 + 5] + up2[(2*j)*12 + 5];
      f1d[6 + j] = v / us;
    } else if (tid >= 77 && tid < 89) {   // dn[12]
      int k = tid - 77;
      f1d[13 + k] = dn2[k*12 + 5] / ds;
    }
  }
}

// ---------------------------------------------------------------------------
// prep_x v2: x[b][ci][y][x] fp32 -> MFMA-native bf16 hi/lo
// [b][y][xb][cih][g][l16][8ci]. float4 global loads, 16B packed stores,
// conflict-free LDS reads (wave covers consecutive xc for fixed ci).
// ---------------------------------------------------------------------------
__global__ __launch_bounds__(256) void prep_x_kernel(
    const float* __restrict__ x,
    __hip_bfloat16* __restrict__ xhi,
    __hip_bfloat16* __restrict__ xlo) {
  __shared__ float tile[64][132];
  int blk = blockIdx.x;
  int y = blk & 127;
  int b = blk >> 7;
  int tid = threadIdx.x;
  // load 64 ci-rows x 32 float4 (coalesced), store b128 to LDS
#pragma unroll
  for (int i = 0; i < 8; ++i) {
    int idx = i*256 + tid;
    int ci = idx >> 5, xf = idx & 31;
    f32x4 v = *(const f32x4*)(x + ((size_t)(b*64 + ci)*128 + y)*128 + 4*xf);
    *(f32x4*)(&tile[ci][4*xf]) = v;
  }
  __syncthreads();
  uint4v* oh = (uint4v*)xhi;
  uint4v* ol = (uint4v*)xlo;
  size_t rowc = (size_t)(b*128 + y)*1024;   // 16B chunks per row = 1024
#pragma unroll
  for (int i = 0; i < 4; ++i) {
    int u = i*256 + tid;                    // 0..1023
    int l16 = u & 15;
    int xb  = (u >> 4) & 7;
    int cih = (u >> 7) & 1;
    int g   = (u >> 8) & 3;
    int ci0 = cih*32 + g*8;
    int xc  = xb*16 + l16;
    uint4v uh, ul;
#pragma unroll
    for (int ep = 0; ep < 4; ++ep) {
      float v0 = tile[ci0 + 2*ep][xc];
      float v1 = tile[ci0 + 2*ep + 1][xc];
      __hip_bfloat16 h0 = __float2bfloat16(v0);
      __hip_bfloat16 h1 = __float2bfloat16(v1);
      __hip_bfloat16 l0 = __float2bfloat16(v0 - __bfloat162float(h0));
      __hip_bfloat16 l1 = __float2bfloat16(v1 - __bfloat162float(h1));
      uh[ep] = (unsigned)*(unsigned short*)&h0 | ((unsigned)*(unsigned short*)&h1 << 16);
      ul[ep] = (unsigned)*(unsigned short*)&l0 | ((unsigned)*(unsigned short*)&l1 << 16);
    }
    size_t chunk = rowc + (size_t)(xb*128 + cih*64 + g*16 + l16);
    oh[chunk] = uh;
    ol[chunk] = ul;
  }
}

// ---------------------------------------------------------------------------
// conv_mfma v4: row-pair waves. Wave = 2 rows x 32 cols x 64 co
// (acc[2r][4ct][2pt]); every w fragment reused across 2 rows x 2 pt:
// 864 MFMA / 240 loads per wave. Grid: 8b x 16rg(8rows) x 4colq = 512 blocks
// x 4 waves (2 blocks/CU, all resident).
// ---------------------------------------------------------------------------
__global__ __launch_bounds__(256, 2) void conv_mfma_kernel(
    const __hip_bfloat16* __restrict__ xhi,  // [8][128][8][2][4][16][8]
    const __hip_bfloat16* __restrict__ xlo,
    const __hip_bfloat16* __restrict__ whi,  // [9][2][4][4][16][8]
    const __hip_bfloat16* __restrict__ wlo,
    const float* __restrict__ bsum,          // [64]
    float* __restrict__ y0) {                // [8][64][128][128]
  int blk = blockIdx.x;
  int colq = blk & 3;
  int rg  = (blk >> 2) & 15;
  int b   = blk >> 6;
  int tid = threadIdx.x;
  int wv  = tid >> 6;
  int lane = tid & 63;
  int l16 = lane & 15;
  int g   = lane >> 4;
  int yr0 = rg*8 + wv*2;                     // rows yr0, yr0+1
  int xb  = colq*2;
  int px0 = colq*32;

  f32x4 acc[2][4][2];
#pragma unroll
  for (int ct = 0; ct < 4; ++ct) {
#pragma unroll
    for (int r = 0; r < 4; ++r) {
      float bv = bsum[ct*16 + g*4 + r];
#pragma unroll
      for (int rr = 0; rr < 2; ++rr)
#pragma unroll
        for (int pt = 0; pt < 2; ++pt) acc[rr][ct][pt][r] = bv;
    }
  }

  const short8 zv8 = {0,0,0,0,0,0,0,0};
  int lofs = (g*16 + l16)*8;                 // per-lane chunk offset (elements)

#pragma unroll
  for (int cih = 0; cih < 2; ++cih) {
    for (int dy = -1; dy <= 1; ++dy) {
      // aligned fragments, both rows, col-blocks xb-1..xb+2
      short8 Fh[2][4], Fl[2][4];
#pragma unroll
      for (int rr = 0; rr < 2; ++rr) {
        int ry = yr0 + rr + dy;
        bool rok = (unsigned)ry < 128u;
        const __hip_bfloat16* rh = xhi + (size_t)(b*128 + ry)*8192;
        const __hip_bfloat16* rl = xlo + (size_t)(b*128 + ry)*8192;
#pragma unroll
        for (int i = 0; i < 4; ++i) {
          int xbF = xb - 1 + i;
          bool ok = rok && ((unsigned)xbF < 8u);
          if (ok) {
            size_t off = (size_t)((xbF*2 + cih)*64)*8 + lofs;
            Fh[rr][i] = *(const short8*)(rh + off);
            Fl[rr][i] = *(const short8*)(rl + off);
          } else {
            Fh[rr][i] = zv8; Fl[rr][i] = zv8;
          }
        }
      }
#pragma unroll
      for (int dxn = 0; dxn < 3; ++dxn) {    // dx = dxn-1
        int tap = (dy + 1)*3 + dxn;
        short8 xh[2][2], xl[2][2];
#pragma unroll
        for (int rr = 0; rr < 2; ++rr)
#pragma unroll
          for (int pt = 0; pt < 2; ++pt) {
            if (dxn == 1) { xh[rr][pt] = Fh[rr][pt + 1]; xl[rr][pt] = Fl[rr][pt + 1]; }
            else if (dxn == 2) {
              xh[rr][pt] = dpp_shift_p1(Fh[rr][pt + 1], Fh[rr][pt + 2]);
              xl[rr][pt] = dpp_shift_p1(Fl[rr][pt + 1], Fl[rr][pt + 2]);
            } else {
              xh[rr][pt] = dpp_shift_m1(Fh[rr][pt + 1], Fh[rr][pt]);
              xl[rr][pt] = dpp_shift_m1(Fl[rr][pt + 1], Fl[rr][pt]);
            }
          }
        const __hip_bfloat16* wb  = whi + (size_t)((tap*2 + cih)*4)*512;
        const __hip_bfloat16* wlb = wlo + (size_t)((tap*2 + cih)*4)*512;
#pragma unroll
        for (int ct = 0; ct < 4; ++ct) {
          short8 wh = *(const short8*)(wb  + (size_t)ct*512 + lofs);
          short8 wl = *(const short8*)(wlb + (size_t)ct*512 + lofs);
#pragma unroll
          for (int rr = 0; rr < 2; ++rr)
#pragma unroll
            for (int pt = 0; pt < 2; ++pt) {
              acc[rr][ct][pt] = __builtin_amdgcn_mfma_f32_16x16x32_bf16(wh, xh[rr][pt], acc[rr][ct][pt], 0, 0, 0);
              acc[rr][ct][pt] = __builtin_amdgcn_mfma_f32_16x16x32_bf16(wl, xh[rr][pt], acc[rr][ct][pt], 0, 0, 0);
              acc[rr][ct][pt] = __builtin_amdgcn_mfma_f32_16x16x32_bf16(wh, xl[rr][pt], acc[rr][ct][pt], 0, 0, 0);
            }
        }
      }
    }
  }

  // store: co = ct*16 + 4*g + r, px = px0 + pt*16 + l16
#pragma unroll
  for (int rr = 0; rr < 2; ++rr) {
    float* yb = y0 + (size_t)b*64*PLANE + (yr0 + rr)*128 + px0;
#pragma unroll
    for (int ct = 0; ct < 4; ++ct)
#pragma unroll
      for (int pt = 0; pt < 2; ++pt)
#pragma unroll
        for (int r = 0; r < 4; ++r) {
          int co = ct*16 + g*4 + r;
          yb[(size_t)co*PLANE + pt*16 + l16] = acc[rr][ct][pt][r];
        }
  }
}

// ---------------------------------------------------------------------------
// upfirdn v3: 4 phases. Order swapped (separable filters commute):
//   0) load y tile (43 x 75, pitch 76)
//   A) VERTICAL polyphase up: Hv[74][75] (pitch 76)
//   B) ROW-FUSED: per Hv row, H-up + lrelu*gain + boundary mask + H-dn
//      entirely in registers -> dh[74][64] (pitch 68)
//   C) VERTICAL dn -> out 32x64
// LDS: y [0,3268) ; dh [0,5032) aliases y (dead) ; Hv [5032,10656).
// Total 42,624 B -> no power-of-2 pitches (76,68 => per-row bank rotation).
// Tile 32x64 out, 512 thr, 4096 blocks.
// ---------------------------------------------------------------------------
#define YOFF  0
#define DHOFF 0
#define HVOFF 5032
#define YP  76
#define HVP 76
#define DHP 68

__global__ __launch_bounds__(512, 4) void upfirdn_kernel(
    const float* __restrict__ y0,    // [512][128][128]
    const float* __restrict__ f1d,   // [25]: e[6], o[7], dn[12]
    float* __restrict__ out) {       // [512][128][128]
  __shared__ float lds[10656];

  int tid   = threadIdx.x;
  int blk   = blockIdx.x;
  int tile  = blk & 7;
  int plane = blk >> 3;
  int ty = tile >> 1, tx = tile & 1;
  int i0 = ty*32, j0 = tx*64;
  const float* yp = y0 + (size_t)plane*PLANE;

  float ef[6], of[7], dnf[12];
#pragma unroll
  for (int j = 0; j < 6; ++j) ef[j] = f1d[j];
#pragma unroll
  for (int j = 0; j < 7; ++j) of[j] = f1d[6 + j];
#pragma unroll
  for (int k = 0; k < 12; ++k) dnf[k] = f1d[13 + k];

  // phase 0: y tile rows i0-5..i0+37 (43), cols j0-5..j0+70 (76 incl pad col)
  for (int p = tid; p < 43*76; p += 512) {
    int r = p / 76, c = p - r*76;
    int gy = i0 - 5 + r, gx = j0 - 5 + c;
    float v = 0.f;
    if (((unsigned)gy < 128u) && ((unsigned)gx < 128u)) v = yp[gy*IN_SZ + gx];
    lds[YOFF + r*YP + c] = v;
  }
  __syncthreads();

  // phase A: vertical polyphase up. Hv[qyi][c] = sum_j f[j]*y[(qyi>>1)+j][c],
  // f = e (even qyi) / o (odd). Items: 19 row-groups x 19 col-quads = 361.
  if (tid < 361) {
    int g = tid / 19, cq = tid - (tid / 19)*19;
    f32x4 yv[8];
#pragma unroll
    for (int r = 0; r < 8; ++r) {
      int row = 2*g + r;
      if (row > 42) row = 42;                  // clamp (unused rows only)
      yv[r] = *(const f32x4*)(lds + YOFF + row*YP + 4*cq);
    }
#pragma unroll
    for (int s = 0; s < 4; ++s) {
      int qyi = 4*g + s;
      if (qyi < 74) {
        int bb = s >> 1;
        f32x4 a = {0.f, 0.f, 0.f, 0.f};
        if ((s & 1) == 0) {
#pragma unroll
          for (int j = 0; j < 6; ++j) a += ef[j]*yv[bb + j];
        } else {
#pragma unroll
          for (int j = 0; j < 7; ++j) a += of[j]*yv[bb + j];
        }
        *(f32x4*)(lds + HVOFF + qyi*HVP + 4*cq) = a;
      }
    }
  }
  __syncthreads();

  // phase B: per-row fused H-up + lrelu*gain + mask + H-dn, in registers.
  // Item (qyi, jg): dh[qyi][8jg..8jg+7] from Hv[qyi][8jg..8jg+18] via
  // z[m] (m=0..25; z col qxi = 16jg+m; Hv col (qxi>>1)+j = 8jg+(m>>1)+j).
  {
    int Qy0 = 2*i0 - 5, Qx0 = 2*j0 - 5;
    for (int p = tid; p < 74*8; p += 512) {
      int qyi = p >> 3, jg = p & 7;
      float* dhp = lds + DHOFF + qyi*DHP + 8*jg;
      int qy = Qy0 + qyi;
      if ((unsigned)qy >= 256u) {
        f32x4 zz = {0.f, 0.f, 0.f, 0.f};
        *(f32x4*)dhp = zz;
        *(f32x4*)(dhp + 4) = zz;
      } else {
        float hv[20];
        const float* hp = lds + HVOFF + qyi*HVP + 8*jg;
#pragma unroll
        for (int i = 0; i < 5; ++i) *(f32x4*)(hv + 4*i) = *(const f32x4*)(hp + 4*i);
        int qxb = Qx0 + 16*jg;
        float z[26];
#pragma unroll
        for (int m = 0; m < 26; ++m) {
          int t = m >> 1;
          float a = 0.f;
          if ((m & 1) == 0) {
#pragma unroll
            for (int j = 0; j < 6; ++j) a += ef[j]*hv[t + j];
          } else {
#pragma unroll
            for (int j = 0; j < 7; ++j) a += of[j]*hv[t + j];
          }
          a = (a >= 0.f ? a : 0.2f*a) * 1.4142135623730951f;
          z[m] = ((unsigned)(qxb + m) < 256u) ? a : 0.f;
        }
        float dv[8];
#pragma unroll
        for (int d = 0; d < 8; ++d) {
          float a = 0.f;
#pragma unroll
          for (int k = 0; k < 12; ++k) a += dnf[k]*z[2*d + k];
          dv[d] = a;
        }
        f32x4 o0 = {dv[0], dv[1], dv[2], dv[3]};
        f32x4 o1 = {dv[4], dv[5], dv[6], dv[7]};
        *(f32x4*)dhp = o0;
        *(f32x4*)(dhp + 4) = o1;
      }
    }
  }
  __syncthreads();

  // phase C: vertical dn. out[i0+4gi+s][j0+j] = sum_k dn[k]*dh[8gi+2s+k][j].
  {
    int gi = tid >> 6, j = tid & 63;
    float dreg[18];
#pragma unroll
    for (int r = 0; r < 18; ++r) dreg[r] = lds[DHOFF + (8*gi + r)*DHP + j];
    float* op = out + (size_t)plane*PLANE + (i0 + 4*gi)*IN_SZ + (j0 + j);
#pragma unroll
    for (int s = 0; s < 4; ++s) {
      float a = 0.f;
#pragma unroll
      for (int k = 0; k < 12; ++k) a += dnf[k]*dreg[2*s + k];
      op[s*IN_SZ] = a;
    }
  }
}

// ---------------------------------------------------------------------------
extern "C" void kernel_launch(void* const* d_in, const int* in_sizes, int n_in,
                              void* d_out, int out_size, void* d_ws, size_t ws_size,
                              hipStream_t stream) {
  const float* x      = (const float*)d_in[0];
  const float* conv_w = (const float*)d_in[1];
  const float* conv_b = (const float*)d_in[2];
  const float* bias   = (const float*)d_in[3];
  const float* up2    = (const float*)d_in[4];
  const float* dn2    = (const float*)d_in[5];
  float* outp = (float*)d_out;

  char* ws = (char*)d_ws;
  float* y0  = (float*)(ws);
  __hip_bfloat16* whi = (__hip_bfloat16*)(ws + Y0B);
  __hip_bfloat16* wlo = (__hip_bfloat16*)(ws + Y0B + WHB);
  float* bsum = (float*)(ws + Y0B + 2*WHB);
  float* f1d  = (float*)(ws + Y0B + 2*WHB + 256);

  // x hi/lo planes live in d_out as scratch (2 x 16.78MB = out bytes);
  // dead before upfirdn writes the real output.
  __hip_bfloat16* xhi = (__hip_bfloat16*)d_out;
  __hip_bfloat16* xlo = xhi + (size_t)NB*PLANE*64;

  prep_w_kernel<<<144, 256, 0, stream>>>(conv_w, conv_b, bias, up2, dn2, whi, wlo, bsum, f1d);
  prep_x_kernel<<<1024, 256, 0, stream>>>(x, xhi, xlo);
  conv_mfma_kernel<<<512, 256, 0, stream>>>(xhi, xlo, whi, wlo, bsum, y0);
  upfirdn_kernel<<<4096, 512, 0, stream>>>(y0, f1d, outp);
}